// Round 16
// baseline (154.441 us; speedup 1.0000x reference)
//
#include <hip/hip_runtime.h>
#include <hip/hip_bf16.h>

typedef unsigned short u16;
typedef unsigned int   u32;
typedef __attribute__((ext_vector_type(8))) short short8;
typedef __attribute__((ext_vector_type(4))) float f32x4;

#define BATCH 2
#define CCH   128
#define HH    96
#define WW    96
#define HWSZ  9216
#define HEADS 8
#define HD    16
#define GROUPS 32
#define EPSV  1e-6f
#define CANARY 0x5AC0FFEEu

static __device__ __forceinline__ u16 f2bf(float f) {
    return __builtin_bit_cast(u16, (__bf16)f);
}
static __device__ __forceinline__ u32 pk2(float a, float b) {
    return (u32)f2bf(a) | ((u32)f2bf(b) << 16);
}
static __device__ __forceinline__ short8 mk8(u32 a, u32 b, u32 c, u32 d) {
    union { short8 v; u32 w[4]; } u; u.w[0]=a; u.w[1]=b; u.w[2]=c; u.w[3]=d; return u.v;
}

// ---------------------------------------------------------------------------
// K1: QKV mega. 864 blocks x 256 thr, 17.4 KB LDS -> 8 blocks/CU, ALL
// co-resident (2048 slots) => tag-spins deadlock-free for any dispatch order.
//   bid<512   : GN partial stats (eighth-groups), atomic publish + release tag
//   512..535  : pack Wq (coalesced, once) -> __threadfence + release tag2
//   536..543  : pack Wp (consumed by proj across kernel boundary)
//   all blocks: spin-acquire {8 stats tags (tid<128)} + {24 Wq tags
//               (tid 128..151)}, then round-11 qkv_fused GEMM body.
// ---------------------------------------------------------------------------
__global__ __launch_bounds__(256) void qkv_mega(const float* __restrict__ x,
                                                const float* __restrict__ gamma,
                                                const float* __restrict__ beta,
                                                const float* __restrict__ qkv_w,
                                                const float* __restrict__ proj_w,
                                                const float* __restrict__ qkv_b,
                                                float* __restrict__ partial,
                                                u32* __restrict__ tags,
                                                u32* __restrict__ tags2,
                                                u16* __restrict__ Wq,
                                                u16* __restrict__ Wp,
                                                u16* __restrict__ qkvp) {
    __shared__ float scale[CCH], shift[CCH];
    __shared__ u16 Xt[16 * 64 * 8];   // 16 KB
    __shared__ float rs[4], rss[4];
    const int bid = blockIdx.x;
    const int tid = threadIdx.x;

    // ---------- phase 1: producers ----------
    if (bid < 512) {
        const float4* base = (const float4*)(x + (size_t)bid * 4608);
        float s = 0.f, ss = 0.f;
        for (int i = tid; i < 1152; i += 256) {
            float4 v = base[i];
            s  += v.x + v.y + v.z + v.w;
            ss += v.x * v.x + v.y * v.y + v.z * v.z + v.w * v.w;
        }
        #pragma unroll
        for (int off = 32; off > 0; off >>= 1) {
            s  += __shfl_down(s, off);
            ss += __shfl_down(ss, off);
        }
        const int wid = tid >> 6, lane = tid & 63;
        if (lane == 0) { rs[wid] = s; rss[wid] = ss; }
        __syncthreads();
        if (tid == 0) {
            const float S  = rs[0] + rs[1] + rs[2] + rs[3];
            const float SS = rss[0] + rss[1] + rss[2] + rss[3];
            u32* pp = (u32*)&partial[2 * bid];
            __hip_atomic_store(pp,     __builtin_bit_cast(u32, S),
                               __ATOMIC_RELAXED, __HIP_MEMORY_SCOPE_AGENT);
            __hip_atomic_store(pp + 1, __builtin_bit_cast(u32, SS),
                               __ATOMIC_RELAXED, __HIP_MEMORY_SCOPE_AGENT);
            __hip_atomic_store(&tags[bid], CANARY,
                               __ATOMIC_RELEASE, __HIP_MEMORY_SCOPE_AGENT);
        }
    } else if (bid < 536) {
        // pack Wq[cb][384][8] (coalesced, one pass total across 24 blocks)
        const int t = (bid - 512) * 256 + tid;   // 0..6143
        const int cb = t / 384, o = t % 384;
        u16 pk[8];
        #pragma unroll
        for (int j = 0; j < 8; ++j) pk[j] = f2bf(qkv_w[o * 128 + cb * 8 + j]);
        uint4 r;
        r.x = (u32)pk[0] | ((u32)pk[1] << 16); r.y = (u32)pk[2] | ((u32)pk[3] << 16);
        r.z = (u32)pk[4] | ((u32)pk[5] << 16); r.w = (u32)pk[6] | ((u32)pk[7] << 16);
        *(uint4*)(Wq + (size_t)t * 8) = r;
        __threadfence();
        __syncthreads();
        if (tid == 0)
            __hip_atomic_store(&tags2[bid - 512], CANARY,
                               __ATOMIC_RELEASE, __HIP_MEMORY_SCOPE_AGENT);
    } else if (bid < 544) {
        // pack Wp[cb][128][8] (consumed by proj_gemm next kernel)
        const int t = (bid - 536) * 256 + tid;   // 0..2047
        const int cb = t >> 7, o = t & 127;
        u16 pk[8];
        #pragma unroll
        for (int j = 0; j < 8; ++j) pk[j] = f2bf(proj_w[o * 128 + cb * 8 + j]);
        uint4 r;
        r.x = (u32)pk[0] | ((u32)pk[1] << 16); r.y = (u32)pk[2] | ((u32)pk[3] << 16);
        r.z = (u32)pk[4] | ((u32)pk[5] << 16); r.w = (u32)pk[6] | ((u32)pk[7] << 16);
        *(uint4*)(Wp + (size_t)t * 8) = r;
    }

    // ---------- phase 2: consumers spin, compute scale/shift ----------
    const int L = (bid & 7) * 108 + (bid >> 3);   // chunk swizzle (864 = 8*108)
    const int b = L / 432;
    const int r = L % 432;
    const int pt = r / 3, ot = r % 3;             // pt: 64-px tile 0..143

    if (tid < CCH) {
        const int c = tid, g = c >> 2, bg = b * GROUPS + g;
        #pragma unroll
        for (int e = 0; e < 8; ++e) {
            while (__hip_atomic_load(&tags[bg * 8 + e],
                                     __ATOMIC_ACQUIRE, __HIP_MEMORY_SCOPE_AGENT)
                   != CANARY) {
                __builtin_amdgcn_s_sleep(2);
            }
        }
        float S = 0.f, SS = 0.f;
        #pragma unroll
        for (int e = 0; e < 8; ++e) {
            u32 a0 = __hip_atomic_load((u32*)&partial[2 * (bg * 8 + e)],
                                       __ATOMIC_RELAXED, __HIP_MEMORY_SCOPE_AGENT);
            u32 a1 = __hip_atomic_load((u32*)&partial[2 * (bg * 8 + e) + 1],
                                       __ATOMIC_RELAXED, __HIP_MEMORY_SCOPE_AGENT);
            S  += __builtin_bit_cast(float, a0);
            SS += __builtin_bit_cast(float, a1);
        }
        const float mean = S * (1.f / 36864.f);
        const float rstd = rsqrtf(SS * (1.f / 36864.f) - mean * mean + EPSV);
        const float sc = rstd * gamma[c];
        scale[c] = sc;
        shift[c] = beta[c] - mean * sc;
    } else if (tid < CCH + 24) {
        while (__hip_atomic_load(&tags2[tid - CCH],
                                 __ATOMIC_ACQUIRE, __HIP_MEMORY_SCOPE_AGENT)
               != CANARY) {
            __builtin_amdgcn_s_sleep(2);
        }
    }
    __syncthreads();

    // ---------- phase 3: round-11 qkv_fused GEMM body ----------
    {
        const int px = tid & 63, chh = tid >> 6;
        const float* xb = x + (size_t)b * CCH * HWSZ + (size_t)pt * 64 + px;
        #pragma unroll
        for (int cbi = 0; cbi < 4; ++cbi) {
            const int cb = chh * 4 + cbi;
            u16 pk[8];
            #pragma unroll
            for (int j = 0; j < 8; ++j) {
                const int c = cb * 8 + j;
                pk[j] = f2bf(__builtin_fmaf(xb[(size_t)c * HWSZ], scale[c], shift[c]));
            }
            uint4 o;
            o.x = (u32)pk[0] | ((u32)pk[1] << 16);
            o.y = (u32)pk[2] | ((u32)pk[3] << 16);
            o.z = (u32)pk[4] | ((u32)pk[5] << 16);
            o.w = (u32)pk[6] | ((u32)pk[7] << 16);
            *(uint4*)&Xt[((size_t)cb * 64 + px) * 8] = o;
        }
    }
    __syncthreads();

    const int l = tid & 63, w = tid >> 6;
    const int OB = ot * 128 + (w & 1) * 64;
    const int PL = (w >> 1) * 32;
    const int q = l >> 4, lo = l & 15;

    float bv[4][4];
    #pragma unroll
    for (int of = 0; of < 4; ++of)
        #pragma unroll
        for (int r2 = 0; r2 < 4; ++r2) bv[of][r2] = qkv_b[OB + of * 16 + q * 4 + r2];

    f32x4 acc[4][2] = {};
    #pragma unroll
    for (int ks = 0; ks < 4; ++ks) {
        const int cb = ks * 4 + q;
        short8 a[4];
        #pragma unroll
        for (int of = 0; of < 4; ++of)
            a[of] = *(const short8*)(Wq + ((size_t)cb * 384 + OB + of * 16 + lo) * 8);
        #pragma unroll
        for (int pf = 0; pf < 2; ++pf) {
            short8 bb = *(const short8*)&Xt[((size_t)cb * 64 + PL + pf * 16 + lo) * 8];
            #pragma unroll
            for (int of = 0; of < 4; ++of)
                acc[of][pf] = __builtin_amdgcn_mfma_f32_16x16x32_bf16(a[of], bb, acc[of][pf], 0, 0, 0);
        }
    }

    #pragma unroll
    for (int of = 0; of < 4; ++of) {
        const int plane = b * 24 + (OB >> 4) + of;
        #pragma unroll
        for (int pf = 0; pf < 2; ++pf) {
            const int p = pt * 64 + PL + pf * 16 + lo;
            uint2 pkt;
            pkt.x = pk2(acc[of][pf][0] + bv[of][0], acc[of][pf][1] + bv[of][1]);
            pkt.y = pk2(acc[of][pf][2] + bv[of][2], acc[of][pf][3] + bv[of][3]);
            *(uint2*)(qkvp + ((size_t)plane * HWSZ + p) * 16 + q * 4) = pkt;
        }
    }
}

// ---------------------------------------------------------------------------
// K2: NATTEN. 836-stride VsT (53,376 B LDS -> 3 blocks/CU, r15-proven) +
// exp2 fold (r10-proven). Otherwise round-11 body.
// ---------------------------------------------------------------------------
__global__ __launch_bounds__(384) void natten_mfma(const u16* __restrict__ qkv,
                                                   u16* __restrict__ attn_out) {
    __shared__ u16 Ks[13 * 64 * 16];   // 26,624 B
    __shared__ u16 VsT[16 * 836];      // 26,752 B
    const int tid = threadIdx.x;
    const int xh = blockIdx.x & 1, yb = blockIdx.x >> 1;
    const int h = blockIdx.y, b = blockIdx.z;
    const int ry0 = min(max(yb * 6 - 3, 0), 83);
    const int rx0 = xh * 32;

    for (int i = tid; i < 3328; i += 384) {
        if (i < 1664) {
            const int px = i >> 1, half = i & 1;
            const int row = px >> 6, col = px & 63;
            const u16* gp = qkv + ((size_t)(b * 24 + 8 + h) * HWSZ
                                 + (ry0 + row) * WW + rx0 + col) * 16 + half * 8;
            *(uint4*)&Ks[px * 16 + half * 8] = *(const uint4*)gp;
        } else {
            const int j2 = i - 1664;
            const int px = j2 >> 1, half = j2 & 1;
            const int row = px >> 6, col = px & 63;
            const u16* gp = qkv + ((size_t)(b * 24 + 16 + h) * HWSZ
                                 + (ry0 + row) * WW + rx0 + col) * 16 + half * 8;
            const uint4 vv = *(const uint4*)gp;
            const int ch0 = half * 8;
            VsT[(ch0 + 0) * 836 + px] = (u16)(vv.x);
            VsT[(ch0 + 1) * 836 + px] = (u16)(vv.x >> 16);
            VsT[(ch0 + 2) * 836 + px] = (u16)(vv.y);
            VsT[(ch0 + 3) * 836 + px] = (u16)(vv.y >> 16);
            VsT[(ch0 + 4) * 836 + px] = (u16)(vv.z);
            VsT[(ch0 + 5) * 836 + px] = (u16)(vv.z >> 16);
            VsT[(ch0 + 6) * 836 + px] = (u16)(vv.w);
            VsT[(ch0 + 7) * 836 + px] = (u16)(vv.w >> 16);
        }
    }
    __syncthreads();

    const int l = tid & 63, wv = tid >> 6;
    const int m = l & 15, q4 = l >> 4;
    const int yq = m >> 3, xq = m & 7;

    for (int j = 0; j < 3; ++j) {
        const int g = wv * 3 + j;
        const int gy = g / 6, gx = g % 6;
        const int y0g = yb * 6 + gy * 2, x0g = xh * 48 + gx * 8;
        const int yabs = y0g + yq, xabs = x0g + xq;
        const int sy = min(max(yabs - 3, 0), 88);
        const int sx = min(max(xabs - 3, 0), 88);
        const int dy0 = min(max(y0g - 3, 0), 88) - ry0;
        const int rd0 = dy0 - (sy - ry0);
        const int cx0 = (min(max(x0g - 3 - rx0, 0), 48)) & ~3;
        const int cd0 = cx0 + q4 * 4 - (sx - rx0);
        const int qpix = yabs * WW + xabs;

        const uint2 qw = *(const uint2*)(qkv + ((size_t)(b * 24 + h) * HWSZ + qpix) * 16 + q4 * 4);
        const short8 qb = mk8(qw.x, qw.y, 0u, 0u);

        const float NEGB = -1e30f;
        const float SC2 = 0.25f * 1.4426950408889634f;   // 1/sqrt(hd) * log2(e)
        float colb[4];
        #pragma unroll
        for (int r = 0; r < 4; ++r) colb[r] = ((u32)(cd0 + r) < 8u) ? 0.f : NEGB;

        float ev[9][4];
        float vs = 0.f;
        #pragma unroll
        for (int t = 0; t < 9; ++t) {
            const int trow = min(dy0 + t, 12);
            const uint2 kk = *(const uint2*)&Ks[(trow * 64 + cx0 + m) * 16 + q4 * 4];
            f32x4 lg = __builtin_amdgcn_mfma_f32_16x16x32_bf16(
                mk8(kk.x, kk.y, kk.x, kk.y), qb, (f32x4){0.f, 0.f, 0.f, 0.f}, 0, 0, 0);
            const float rb = ((u32)(t + rd0) < 8u) ? 0.f : NEGB;
            #pragma unroll
            for (int r = 0; r < 4; ++r) {
                const float e = exp2f(__builtin_fmaf(lg[r], SC2, colb[r] + rb));
                ev[t][r] = e;
                vs += e;
            }
        }
        vs += __shfl_xor(vs, 16);
        vs += __shfl_xor(vs, 32);
        const float inv = 1.0f / vs;

        u32 pd0[9], pd1[9];
        #pragma unroll
        for (int t = 0; t < 9; ++t) {
            pd0[t] = pk2(ev[t][0], ev[t][1]);
            pd1[t] = pk2(ev[t][2], ev[t][3]);
        }

        f32x4 acc = {};
        #pragma unroll
        for (int t = 0; t < 9; ++t) {
            const int trow = min(dy0 + t, 12);
            const uint2 va = *(const uint2*)&VsT[m * 836 + trow * 64 + cx0 + q4 * 4];
            acc = __builtin_amdgcn_mfma_f32_16x16x32_bf16(
                mk8(va.x, va.y, va.x, va.y), mk8(pd0[t], pd1[t], 0u, 0u), acc, 0, 0, 0);
        }

        uint2 od;
        od.x = pk2(acc[0] * inv, acc[1] * inv);
        od.y = pk2(acc[2] * inv, acc[3] * inv);
        *(uint2*)(attn_out + ((size_t)(b * 16 + h * 2 + (q4 >> 1)) * HWSZ + qpix) * 8
                  + (q4 & 1) * 4) = od;
    }
}

// ---------------------------------------------------------------------------
// K3: proj GEMM (round-11 proven; Wp packed by K1 across kernel boundary).
// ---------------------------------------------------------------------------
__global__ __launch_bounds__(256) void proj_gemm(const u16* __restrict__ Wpk,
                                                 const u16* __restrict__ Xpk,
                                                 const float* __restrict__ bias,
                                                 float* __restrict__ out_f32) {
    const int bid = blockIdx.x;              // 0..575
    const int b = bid / 288, pt = bid % 288;
    const int l = threadIdx.x & 63, w = threadIdx.x >> 6;
    const int OB = (w & 1) * 64;
    const int PB = pt * 32 + (w >> 1) * 16;
    const int q = l >> 4, lo = l & 15;
    const u16* Xb = Xpk + (size_t)b * 16 * HWSZ * 8;

    float bv[4][4];
    #pragma unroll
    for (int of = 0; of < 4; ++of)
        #pragma unroll
        for (int r = 0; r < 4; ++r) bv[of][r] = bias[OB + of * 16 + q * 4 + r];

    f32x4 acc[4] = {};
    #pragma unroll
    for (int ks = 0; ks < 4; ++ks) {
        const int cb = ks * 4 + q;
        short8 a[4];
        #pragma unroll
        for (int of = 0; of < 4; ++of)
            a[of] = *(const short8*)(Wpk + ((size_t)cb * 128 + OB + of * 16 + lo) * 8);
        short8 bb = *(const short8*)(Xb + ((size_t)cb * HWSZ + PB + lo) * 8);
        #pragma unroll
        for (int of = 0; of < 4; ++of)
            acc[of] = __builtin_amdgcn_mfma_f32_16x16x32_bf16(a[of], bb, acc[of], 0, 0, 0);
    }

    #pragma unroll
    for (int of = 0; of < 4; ++of) {
        const int p = PB + lo;
        #pragma unroll
        for (int r = 0; r < 4; ++r) {
            const int o = OB + of * 16 + q * 4 + r;
            out_f32[((size_t)(b * 128 + o)) * HWSZ + p] = acc[of][r] + bv[of][r];
        }
    }
}

// ---------------------------------------------------------------------------
extern "C" void kernel_launch(void* const* d_in, const int* in_sizes, int n_in,
                              void* d_out, int out_size, void* d_ws, size_t ws_size,
                              hipStream_t stream) {
    const float* x      = (const float*)d_in[0];
    const float* gamma  = (const float*)d_in[1];
    const float* beta   = (const float*)d_in[2];
    const float* qkv_w  = (const float*)d_in[3];
    const float* qkv_b  = (const float*)d_in[4];
    const float* proj_w = (const float*)d_in[5];
    const float* proj_b = (const float*)d_in[6];
    float* out = (float*)d_out;

    char* wsb = (char*)d_ws;
    float* partial = (float*)wsb;                                   // 4 KB
    u32* tags  = (u32*)(wsb + 4096);                                // 2 KB
    u32* tags2 = (u32*)(wsb + 6144);                                // 96 B (1 KB slot)
    u16* Wq    = (u16*)(wsb + 8192);                                // 49,152 u16
    u16* Wp    = Wq + 16 * 384 * 8;                                 // 16,384 u16
    u16* qkvp  = Wp + 16 * 128 * 8;                                 // 7,077,888 u16
    u16* attnp = qkvp + (size_t)BATCH * 24 * HWSZ * HD;             // 2,359,296 u16

    qkv_mega<<<864, 256, 0, stream>>>(x, gamma, beta, qkv_w, proj_w, qkv_b,
                                      partial, tags, tags2, Wq, Wp, qkvp);

    natten_mfma<<<dim3(32, HEADS, BATCH), 384, 0, stream>>>(qkvp, attnp);

    proj_gemm<<<576, 256, 0, stream>>>(Wp, attnp, proj_b, out);
}

// Round 17
// 41.103 us; speedup vs baseline: 3.7574x; 3.7574x over previous
//
#include <hip/hip_runtime.h>
#include <hip/hip_bf16.h>

typedef unsigned short u16;
typedef unsigned int   u32;
typedef __attribute__((ext_vector_type(8))) short short8;
typedef __attribute__((ext_vector_type(4))) float f32x4;

#define BATCH 2
#define CCH   128
#define HH    96
#define WW    96
#define HWSZ  9216
#define HEADS 8
#define HD    16
#define GROUPS 32
#define EPSV  1e-6f

// fp32 -> bf16 RNE via hardware convert
static __device__ __forceinline__ u16 f2bf(float f) {
    return __builtin_bit_cast(u16, (__bf16)f);
}
static __device__ __forceinline__ u32 pk2(float a, float b) {
    return (u32)f2bf(a) | ((u32)f2bf(b) << 16);
}
static __device__ __forceinline__ short8 mk8(u32 a, u32 b, u32 c, u32 d) {
    union { short8 v; u32 w[4]; } u; u.w[0]=a; u.w[1]=b; u.w[2]=c; u.w[3]=d; return u.v;
}

// ---------------------------------------------------------------------------
// Fused: GN partial stats (blocks 0..511, one EIGHTH of a (b,g) group each)
// + weight packing (blocks 512..543). Round-11 proven.
// ---------------------------------------------------------------------------
__global__ __launch_bounds__(256) void gn_wpack(const float* __restrict__ x,
                                                float* __restrict__ partial,
                                                const float* __restrict__ qkv_w,
                                                const float* __restrict__ proj_w,
                                                u16* __restrict__ Wq, u16* __restrict__ Wp) {
    if (blockIdx.x < 512) {
        const int bq = blockIdx.x;
        const float4* base = (const float4*)(x + (size_t)bq * 4608);
        float s = 0.f, ss = 0.f;
        for (int i = threadIdx.x; i < 1152; i += 256) {
            float4 v = base[i];
            s  += v.x + v.y + v.z + v.w;
            ss += v.x * v.x + v.y * v.y + v.z * v.z + v.w * v.w;
        }
        #pragma unroll
        for (int off = 32; off > 0; off >>= 1) {
            s  += __shfl_down(s, off);
            ss += __shfl_down(ss, off);
        }
        __shared__ float rs[4], rss[4];
        const int wid = threadIdx.x >> 6, lane = threadIdx.x & 63;
        if (lane == 0) { rs[wid] = s; rss[wid] = ss; }
        __syncthreads();
        if (threadIdx.x == 0) {
            partial[2 * bq]     = rs[0] + rs[1] + rs[2] + rs[3];
            partial[2 * bq + 1] = rss[0] + rss[1] + rss[2] + rss[3];
        }
    } else {
        const int t = (blockIdx.x - 512) * 256 + threadIdx.x;
        if (t < 16 * 384) {
            int cb = t / 384, o = t % 384;
            u16 pk[8];
            #pragma unroll
            for (int j = 0; j < 8; ++j) pk[j] = f2bf(qkv_w[o * 128 + cb * 8 + j]);
            uint4 r;
            r.x = (u32)pk[0] | ((u32)pk[1] << 16); r.y = (u32)pk[2] | ((u32)pk[3] << 16);
            r.z = (u32)pk[4] | ((u32)pk[5] << 16); r.w = (u32)pk[6] | ((u32)pk[7] << 16);
            *(uint4*)(Wq + (size_t)t * 8) = r;
        } else if (t < 16 * 384 + 16 * 128) {
            int i = t - 16 * 384;
            int cb = i / 128, o = i % 128;
            u16 pk[8];
            #pragma unroll
            for (int j = 0; j < 8; ++j) pk[j] = f2bf(proj_w[o * 128 + cb * 8 + j]);
            uint4 r;
            r.x = (u32)pk[0] | ((u32)pk[1] << 16); r.y = (u32)pk[2] | ((u32)pk[3] << 16);
            r.z = (u32)pk[4] | ((u32)pk[5] << 16); r.w = (u32)pk[6] | ((u32)pk[7] << 16);
            *(uint4*)(Wp + (size_t)i * 8) = r;
        }
    }
}

// ---------------------------------------------------------------------------
// QKV GEMM fused with GroupNorm-normalize staging. Round-11 proven.
// ---------------------------------------------------------------------------
__global__ __launch_bounds__(256) void qkv_fused(const float* __restrict__ x,
                                                 const float* __restrict__ partial,
                                                 const float* __restrict__ gamma,
                                                 const float* __restrict__ beta,
                                                 const u16* __restrict__ Wq,
                                                 const float* __restrict__ qkv_b,
                                                 u16* __restrict__ qkvp) {
    __shared__ float scale[CCH], shift[CCH];
    __shared__ u16 Xt[16 * 64 * 8];   // 16 KB
    const int t = threadIdx.x;
    const int pph = blockIdx.x;                   // 0..863
    const int L = (pph & 7) * 108 + (pph >> 3);   // chunk swizzle (864 = 8*108)
    const int b = L / 432;
    const int r = L % 432;
    const int pt = r / 3, ot = r % 3;             // pt: 64-px tile 0..143

    if (t < CCH) {
        const int c = t, g = c >> 2, bg = b * GROUPS + g;
        float S = 0.f, SS = 0.f;
        #pragma unroll
        for (int e = 0; e < 8; ++e) {
            S  += partial[2 * (bg * 8 + e)];
            SS += partial[2 * (bg * 8 + e) + 1];
        }
        const float mean = S * (1.f / 36864.f);
        const float rstd = rsqrtf(SS * (1.f / 36864.f) - mean * mean + EPSV);
        const float sc = rstd * gamma[c];
        scale[c] = sc;
        shift[c] = beta[c] - mean * sc;
    }
    __syncthreads();

    {
        const int px = t & 63, chh = t >> 6;
        const float* xb = x + (size_t)b * CCH * HWSZ + (size_t)pt * 64 + px;
        #pragma unroll
        for (int cbi = 0; cbi < 4; ++cbi) {
            const int cb = chh * 4 + cbi;
            u16 pk[8];
            #pragma unroll
            for (int j = 0; j < 8; ++j) {
                const int c = cb * 8 + j;
                pk[j] = f2bf(__builtin_fmaf(xb[(size_t)c * HWSZ], scale[c], shift[c]));
            }
            uint4 o;
            o.x = (u32)pk[0] | ((u32)pk[1] << 16);
            o.y = (u32)pk[2] | ((u32)pk[3] << 16);
            o.z = (u32)pk[4] | ((u32)pk[5] << 16);
            o.w = (u32)pk[6] | ((u32)pk[7] << 16);
            *(uint4*)&Xt[((size_t)cb * 64 + px) * 8] = o;
        }
    }
    __syncthreads();

    const int l = t & 63, w = t >> 6;
    const int OB = ot * 128 + (w & 1) * 64;
    const int PL = (w >> 1) * 32;
    const int q = l >> 4, lo = l & 15;

    float bv[4][4];
    #pragma unroll
    for (int of = 0; of < 4; ++of)
        #pragma unroll
        for (int r2 = 0; r2 < 4; ++r2) bv[of][r2] = qkv_b[OB + of * 16 + q * 4 + r2];

    f32x4 acc[4][2] = {};
    #pragma unroll
    for (int ks = 0; ks < 4; ++ks) {
        const int cb = ks * 4 + q;
        short8 a[4];
        #pragma unroll
        for (int of = 0; of < 4; ++of)
            a[of] = *(const short8*)(Wq + ((size_t)cb * 384 + OB + of * 16 + lo) * 8);
        #pragma unroll
        for (int pf = 0; pf < 2; ++pf) {
            short8 bb = *(const short8*)&Xt[((size_t)cb * 64 + PL + pf * 16 + lo) * 8];
            #pragma unroll
            for (int of = 0; of < 4; ++of)
                acc[of][pf] = __builtin_amdgcn_mfma_f32_16x16x32_bf16(a[of], bb, acc[of][pf], 0, 0, 0);
        }
    }

    #pragma unroll
    for (int of = 0; of < 4; ++of) {
        const int plane = b * 24 + (OB >> 4) + of;
        #pragma unroll
        for (int pf = 0; pf < 2; ++pf) {
            const int p = pt * 64 + PL + pf * 16 + lo;
            uint2 pkt;
            pkt.x = pk2(acc[of][pf][0] + bv[of][0], acc[of][pf][1] + bv[of][1]);
            pkt.y = pk2(acc[of][pf][2] + bv[of][2], acc[of][pf][3] + bv[of][3]);
            *(uint2*)(qkvp + ((size_t)plane * HWSZ + p) * 16 + q * 4) = pkt;
        }
    }
}

// ---------------------------------------------------------------------------
// Proj GEMM: 576 blocks. Round-11 proven.
// ---------------------------------------------------------------------------
__global__ __launch_bounds__(256) void proj_gemm(const u16* __restrict__ Wpk,
                                                 const u16* __restrict__ Xpk,
                                                 const float* __restrict__ bias,
                                                 float* __restrict__ out_f32) {
    const int bid = blockIdx.x;              // 0..575
    const int b = bid / 288, pt = bid % 288;
    const int l = threadIdx.x & 63, w = threadIdx.x >> 6;
    const int OB = (w & 1) * 64;
    const int PB = pt * 32 + (w >> 1) * 16;
    const int q = l >> 4, lo = l & 15;
    const u16* Xb = Xpk + (size_t)b * 16 * HWSZ * 8;

    float bv[4][4];
    #pragma unroll
    for (int of = 0; of < 4; ++of)
        #pragma unroll
        for (int r = 0; r < 4; ++r) bv[of][r] = bias[OB + of * 16 + q * 4 + r];

    f32x4 acc[4] = {};
    #pragma unroll
    for (int ks = 0; ks < 4; ++ks) {
        const int cb = ks * 4 + q;
        short8 a[4];
        #pragma unroll
        for (int of = 0; of < 4; ++of)
            a[of] = *(const short8*)(Wpk + ((size_t)cb * 128 + OB + of * 16 + lo) * 8);
        short8 bb = *(const short8*)(Xb + ((size_t)cb * HWSZ + PB + lo) * 8);
        #pragma unroll
        for (int of = 0; of < 4; ++of)
            acc[of] = __builtin_amdgcn_mfma_f32_16x16x32_bf16(a[of], bb, acc[of], 0, 0, 0);
    }

    #pragma unroll
    for (int of = 0; of < 4; ++of) {
        const int p = PB + lo;
        #pragma unroll
        for (int r = 0; r < 4; ++r) {
            const int o = OB + of * 16 + q * 4 + r;
            out_f32[((size_t)(b * 128 + o)) * HWSZ + p] = acc[of][r] + bv[of][r];
        }
    }
}

// ---------------------------------------------------------------------------
// MFMA NATTEN — round-11 body, ONE change: VsT stride 840 -> 836 so LDS =
// 53,376 B -> 3 blocks/CU (18 waves/CU vs 12). Stride-836 layout proven
// correct in rounds 15/16. Alignment: VsT index m*836 + trow*64 + cx0 + q4*4
// has all terms multiple-of-4 u16 => 8 B aligned b64 reads.
// ---------------------------------------------------------------------------
__global__ __launch_bounds__(384) void natten_mfma(const u16* __restrict__ qkv,
                                                   u16* __restrict__ attn_out) {
    __shared__ u16 Ks[13 * 64 * 16];   // 26,624 B
    __shared__ u16 VsT[16 * 836];      // 26,752 B
    const int tid = threadIdx.x;
    const int xh = blockIdx.x & 1, yb = blockIdx.x >> 1;
    const int h = blockIdx.y, b = blockIdx.z;
    const int ry0 = min(max(yb * 6 - 3, 0), 83);
    const int rx0 = xh * 32;

    for (int i = tid; i < 3328; i += 384) {
        if (i < 1664) {
            const int px = i >> 1, half = i & 1;
            const int row = px >> 6, col = px & 63;
            const u16* gp = qkv + ((size_t)(b * 24 + 8 + h) * HWSZ
                                 + (ry0 + row) * WW + rx0 + col) * 16 + half * 8;
            *(uint4*)&Ks[px * 16 + half * 8] = *(const uint4*)gp;
        } else {
            const int j2 = i - 1664;
            const int px = j2 >> 1, half = j2 & 1;
            const int row = px >> 6, col = px & 63;
            const u16* gp = qkv + ((size_t)(b * 24 + 16 + h) * HWSZ
                                 + (ry0 + row) * WW + rx0 + col) * 16 + half * 8;
            const uint4 vv = *(const uint4*)gp;
            const int ch0 = half * 8;
            VsT[(ch0 + 0) * 836 + px] = (u16)(vv.x);
            VsT[(ch0 + 1) * 836 + px] = (u16)(vv.x >> 16);
            VsT[(ch0 + 2) * 836 + px] = (u16)(vv.y);
            VsT[(ch0 + 3) * 836 + px] = (u16)(vv.y >> 16);
            VsT[(ch0 + 4) * 836 + px] = (u16)(vv.z);
            VsT[(ch0 + 5) * 836 + px] = (u16)(vv.z >> 16);
            VsT[(ch0 + 6) * 836 + px] = (u16)(vv.w);
            VsT[(ch0 + 7) * 836 + px] = (u16)(vv.w >> 16);
        }
    }
    __syncthreads();

    const int l = tid & 63, wv = tid >> 6;
    const int m = l & 15, q4 = l >> 4;
    const int yq = m >> 3, xq = m & 7;

    for (int j = 0; j < 3; ++j) {
        const int g = wv * 3 + j;
        const int gy = g / 6, gx = g % 6;
        const int y0g = yb * 6 + gy * 2, x0g = xh * 48 + gx * 8;
        const int yabs = y0g + yq, xabs = x0g + xq;
        const int sy = min(max(yabs - 3, 0), 88);
        const int sx = min(max(xabs - 3, 0), 88);
        const int dy0 = min(max(y0g - 3, 0), 88) - ry0;
        const int rd0 = dy0 - (sy - ry0);
        const int cx0 = (min(max(x0g - 3 - rx0, 0), 48)) & ~3;
        const int cd0 = cx0 + q4 * 4 - (sx - rx0);
        const int qpix = yabs * WW + xabs;

        const uint2 qw = *(const uint2*)(qkv + ((size_t)(b * 24 + h) * HWSZ + qpix) * 16 + q4 * 4);
        const short8 qb = mk8(qw.x, qw.y, 0u, 0u);

        const float NEGB = -1e30f;
        float colb[4];
        #pragma unroll
        for (int r = 0; r < 4; ++r) colb[r] = ((u32)(cd0 + r) < 8u) ? 0.f : NEGB;

        float ev[9][4];
        float vs = 0.f;
        #pragma unroll
        for (int t = 0; t < 9; ++t) {
            const int trow = min(dy0 + t, 12);
            const uint2 kk = *(const uint2*)&Ks[(trow * 64 + cx0 + m) * 16 + q4 * 4];
            f32x4 lg = __builtin_amdgcn_mfma_f32_16x16x32_bf16(
                mk8(kk.x, kk.y, kk.x, kk.y), qb, (f32x4){0.f, 0.f, 0.f, 0.f}, 0, 0, 0);
            const float rb = ((u32)(t + rd0) < 8u) ? 0.f : NEGB;
            #pragma unroll
            for (int r = 0; r < 4; ++r) {
                const float e = __expf(__builtin_fmaf(lg[r], 0.25f, colb[r] + rb));
                ev[t][r] = e;
                vs += e;
            }
        }
        vs += __shfl_xor(vs, 16);
        vs += __shfl_xor(vs, 32);
        const float inv = 1.0f / vs;

        u32 pd0[9], pd1[9];
        #pragma unroll
        for (int t = 0; t < 9; ++t) {
            pd0[t] = pk2(ev[t][0], ev[t][1]);
            pd1[t] = pk2(ev[t][2], ev[t][3]);
        }

        f32x4 acc = {};
        #pragma unroll
        for (int t = 0; t < 9; ++t) {
            const int trow = min(dy0 + t, 12);
            const uint2 va = *(const uint2*)&VsT[m * 836 + trow * 64 + cx0 + q4 * 4];
            acc = __builtin_amdgcn_mfma_f32_16x16x32_bf16(
                mk8(va.x, va.y, va.x, va.y), mk8(pd0[t], pd1[t], 0u, 0u), acc, 0, 0, 0);
        }

        uint2 od;
        od.x = pk2(acc[0] * inv, acc[1] * inv);
        od.y = pk2(acc[2] * inv, acc[3] * inv);
        *(uint2*)(attn_out + ((size_t)(b * 16 + h * 2 + (q4 >> 1)) * HWSZ + qpix) * 8
                  + (q4 & 1) * 4) = od;
    }
}

// ---------------------------------------------------------------------------
extern "C" void kernel_launch(void* const* d_in, const int* in_sizes, int n_in,
                              void* d_out, int out_size, void* d_ws, size_t ws_size,
                              hipStream_t stream) {
    const float* x      = (const float*)d_in[0];
    const float* gamma  = (const float*)d_in[1];
    const float* beta   = (const float*)d_in[2];
    const float* qkv_w  = (const float*)d_in[3];
    const float* qkv_b  = (const float*)d_in[4];
    const float* proj_w = (const float*)d_in[5];
    const float* proj_b = (const float*)d_in[6];
    float* out = (float*)d_out;

    char* wsb = (char*)d_ws;
    float* partial = (float*)wsb;                                   // 1024 f32
    u16* Wq    = (u16*)(wsb + 8192);                                // 49,152 u16
    u16* Wp    = Wq + 16 * 384 * 8;                                 // 16,384 u16
    u16* qkvp  = Wp + 16 * 128 * 8;                                 // 7,077,888 u16 (24 planes)
    u16* attnp = qkvp + (size_t)BATCH * 24 * HWSZ * HD;             // 2,359,296 u16

    gn_wpack<<<544, 256, 0, stream>>>(x, partial, qkv_w, proj_w, Wq, Wp);

    qkv_fused<<<864, 256, 0, stream>>>(x, partial, gamma, beta, Wq, qkv_b, qkvp);

    natten_mfma<<<dim3(32, HEADS, BATCH), 384, 0, stream>>>(qkvp, attnp);

    proj_gemm<<<576, 256, 0, stream>>>(Wp, attnp, proj_b, out);
}